// Round 1
// baseline (170.393 us; speedup 1.0000x reference)
//
#include <hip/hip_runtime.h>

// EmbeddingBagCollection: 4 tables, W[1M,64] fp32, mean-pool over jagged bags.
// Input order (setup_inputs dict order): W0,values0,offsets0, W1,values1,offsets1, ...
// Output: [B, 4*64] fp32, table t occupies columns [t*64, (t+1)*64).

#define NBAGS 8192
#define DIM 64

__global__ __launch_bounds__(256) void ebc_kernel(
    const float* __restrict__ W0, const int* __restrict__ v0, const int* __restrict__ o0,
    const float* __restrict__ W1, const int* __restrict__ v1, const int* __restrict__ o1,
    const float* __restrict__ W2, const int* __restrict__ v2, const int* __restrict__ o2,
    const float* __restrict__ W3, const int* __restrict__ v3, const int* __restrict__ o3,
    float* __restrict__ out)
{
    const int table = threadIdx.x >> 6;   // wave id within block = table id
    const int lane  = threadIdx.x & 63;   // embedding dim
    const int bag   = blockIdx.x;         // one bag per block

    const float* W; const int* vals; const int* offs;
    if      (table == 0) { W = W0; vals = v0; offs = o0; }
    else if (table == 1) { W = W1; vals = v1; offs = o1; }
    else if (table == 2) { W = W2; vals = v2; offs = o2; }
    else                 { W = W3; vals = v3; offs = o3; }

    const int start = offs[bag];
    const int end   = offs[bag + 1];

    float acc0 = 0.f, acc1 = 0.f;

    // Prefetch up to 64 indices per chunk via lanes, broadcast with shfl.
    for (int base = start; base < end; base += 64) {
        const int rem = end - base;
        const int n = rem < 64 ? rem : 64;
        int v = 0;
        if (lane < n) v = vals[base + lane];
        int j = 0;
        for (; j + 1 < n; j += 2) {
            const int i0 = __shfl(v, j);
            const int i1 = __shfl(v, j + 1);
            acc0 += W[(size_t)i0 * DIM + lane];   // coalesced 256B per wave
            acc1 += W[(size_t)i1 * DIM + lane];
        }
        if (j < n) {
            const int i0 = __shfl(v, j);
            acc0 += W[(size_t)i0 * DIM + lane];
        }
    }

    const int cnt = end - start;
    const float inv = cnt > 0 ? 1.0f / (float)cnt : 0.0f;  // empty bag -> 0
    out[(size_t)bag * (4 * DIM) + table * DIM + lane] = (acc0 + acc1) * inv;
}

extern "C" void kernel_launch(void* const* d_in, const int* in_sizes, int n_in,
                              void* d_out, int out_size, void* d_ws, size_t ws_size,
                              hipStream_t stream) {
    const float* W0 = (const float*)d_in[0];
    const int*   v0 = (const int*)  d_in[1];
    const int*   o0 = (const int*)  d_in[2];
    const float* W1 = (const float*)d_in[3];
    const int*   v1 = (const int*)  d_in[4];
    const int*   o1 = (const int*)  d_in[5];
    const float* W2 = (const float*)d_in[6];
    const int*   v2 = (const int*)  d_in[7];
    const int*   o2 = (const int*)  d_in[8];
    const float* W3 = (const float*)d_in[9];
    const int*   v3 = (const int*)  d_in[10];
    const int*   o3 = (const int*)  d_in[11];
    float* out = (float*)d_out;

    ebc_kernel<<<NBAGS, 256, 0, stream>>>(W0, v0, o0, W1, v1, o1,
                                          W2, v2, o2, W3, v3, o3, out);
}

// Round 2
// 111.195 us; speedup vs baseline: 1.5324x; 1.5324x over previous
//
#include <hip/hip_runtime.h>

// EmbeddingBagCollection: 4 tables, W[1M,64] fp32, mean-pool over jagged bags.
// Mapping: block = bag, wave = table, lane = 16*g + s:
//   group g (0..3) handles row j+g of each 4-row pack, slot s holds floats [4s,4s+4).
// One wave load instruction = 4 rows x 256B = 1KB; unroll x4 => 4KB in flight/wave.

#define NBAGS 8192
#define DIM 64

__global__ __launch_bounds__(256) void ebc_kernel(
    const float* __restrict__ W0, const int* __restrict__ v0, const int* __restrict__ o0,
    const float* __restrict__ W1, const int* __restrict__ v1, const int* __restrict__ o1,
    const float* __restrict__ W2, const int* __restrict__ v2, const int* __restrict__ o2,
    const float* __restrict__ W3, const int* __restrict__ v3, const int* __restrict__ o3,
    float* __restrict__ out)
{
    const int table = threadIdx.x >> 6;   // wave id within block = table id
    const int lane  = threadIdx.x & 63;
    const int g     = lane >> 4;          // row group 0..3
    const int s     = lane & 15;          // float4 slot within row
    const int bag   = blockIdx.x;

    const float* W; const int* vals; const int* offs;
    if      (table == 0) { W = W0; vals = v0; offs = o0; }
    else if (table == 1) { W = W1; vals = v1; offs = o1; }
    else if (table == 2) { W = W2; vals = v2; offs = o2; }
    else                 { W = W3; vals = v3; offs = o3; }

    const int start = offs[bag];
    const int end   = offs[bag + 1];

    float4 a0 = {0,0,0,0}, a1 = {0,0,0,0}, a2 = {0,0,0,0}, a3 = {0,0,0,0};

    for (int base = start; base < end; base += 64) {
        const int rem = end - base;
        const int n = rem < 64 ? rem : 64;
        int v = 0;
        if (lane < n) v = vals[base + lane];   // 64 indices prefetched per chunk
        for (int j = 0; j < n; j += 16) {
            const int r0 = j + g, r1 = j + g + 4, r2 = j + g + 8, r3 = j + g + 12;
            const int i0 = __shfl(v, r0);
            const int i1 = __shfl(v, r1);
            const int i2 = __shfl(v, r2);
            const int i3 = __shfl(v, r3);
            if (r0 < n) { const float4 t = *(const float4*)(W + (size_t)i0 * DIM + s * 4);
                          a0.x += t.x; a0.y += t.y; a0.z += t.z; a0.w += t.w; }
            if (r1 < n) { const float4 t = *(const float4*)(W + (size_t)i1 * DIM + s * 4);
                          a1.x += t.x; a1.y += t.y; a1.z += t.z; a1.w += t.w; }
            if (r2 < n) { const float4 t = *(const float4*)(W + (size_t)i2 * DIM + s * 4);
                          a2.x += t.x; a2.y += t.y; a2.z += t.z; a2.w += t.w; }
            if (r3 < n) { const float4 t = *(const float4*)(W + (size_t)i3 * DIM + s * 4);
                          a3.x += t.x; a3.y += t.y; a3.z += t.z; a3.w += t.w; }
        }
    }

    // Combine the 4 unroll accumulators, then butterfly-reduce across row groups.
    float4 acc;
    acc.x = (a0.x + a1.x) + (a2.x + a3.x);
    acc.y = (a0.y + a1.y) + (a2.y + a3.y);
    acc.z = (a0.z + a1.z) + (a2.z + a3.z);
    acc.w = (a0.w + a1.w) + (a2.w + a3.w);

    acc.x += __shfl_xor(acc.x, 16); acc.y += __shfl_xor(acc.y, 16);
    acc.z += __shfl_xor(acc.z, 16); acc.w += __shfl_xor(acc.w, 16);
    acc.x += __shfl_xor(acc.x, 32); acc.y += __shfl_xor(acc.y, 32);
    acc.z += __shfl_xor(acc.z, 32); acc.w += __shfl_xor(acc.w, 32);

    const int cnt = end - start;
    const float inv = cnt > 0 ? 1.0f / (float)cnt : 0.0f;  // empty bag -> zeros

    if (g == 0) {
        float4 r;
        r.x = acc.x * inv; r.y = acc.y * inv; r.z = acc.z * inv; r.w = acc.w * inv;
        *(float4*)(out + (size_t)bag * (4 * DIM) + table * DIM + s * 4) = r;
    }
}

extern "C" void kernel_launch(void* const* d_in, const int* in_sizes, int n_in,
                              void* d_out, int out_size, void* d_ws, size_t ws_size,
                              hipStream_t stream) {
    const float* W0 = (const float*)d_in[0];
    const int*   v0 = (const int*)  d_in[1];
    const int*   o0 = (const int*)  d_in[2];
    const float* W1 = (const float*)d_in[3];
    const int*   v1 = (const int*)  d_in[4];
    const int*   o1 = (const int*)  d_in[5];
    const float* W2 = (const float*)d_in[6];
    const int*   v2 = (const int*)  d_in[7];
    const int*   o2 = (const int*)  d_in[8];
    const float* W3 = (const float*)d_in[9];
    const int*   v3 = (const int*)  d_in[10];
    const int*   o3 = (const int*)  d_in[11];
    float* out = (float*)d_out;

    ebc_kernel<<<NBAGS, 256, 0, stream>>>(W0, v0, o0, W1, v1, o1,
                                          W2, v2, o2, W3, v3, o3, out);
}

// Round 3
// 76.927 us; speedup vs baseline: 2.2150x; 1.4455x over previous
//
#include <hip/hip_runtime.h>

// EmbeddingBagCollection: 4 tables, W[1M,64] fp32, mean-pool over jagged bags.
// block = bag, wave = table, lane = 16*g + s (g=row group, s=float4 slot).
// Per 64-index chunk: 16 branch-free float4 gathers (rows r=4k+g, clamped) are
// issued back-to-back -> 16 KB in flight per wave; contributions weighted by
// (r < n) so clamped duplicates add zero. Epilogue: shfl_xor butterfly over g.

#define NBAGS 8192
#define DIM 64

__global__ __launch_bounds__(256) void ebc_kernel(
    const float* __restrict__ W0, const int* __restrict__ v0, const int* __restrict__ o0,
    const float* __restrict__ W1, const int* __restrict__ v1, const int* __restrict__ o1,
    const float* __restrict__ W2, const int* __restrict__ v2, const int* __restrict__ o2,
    const float* __restrict__ W3, const int* __restrict__ v3, const int* __restrict__ o3,
    float* __restrict__ out)
{
    const int table = threadIdx.x >> 6;   // wave id within block = table id
    const int lane  = threadIdx.x & 63;
    const int g     = lane >> 4;          // row group 0..3
    const int s     = lane & 15;          // float4 slot within row
    const int bag   = blockIdx.x;

    const float* W; const int* vals; const int* offs;
    if      (table == 0) { W = W0; vals = v0; offs = o0; }
    else if (table == 1) { W = W1; vals = v1; offs = o1; }
    else if (table == 2) { W = W2; vals = v2; offs = o2; }
    else                 { W = W3; vals = v3; offs = o3; }

    const int start = offs[bag];
    const int end   = offs[bag + 1];

    float4 acc0 = {0,0,0,0}, acc1 = {0,0,0,0}, acc2 = {0,0,0,0}, acc3 = {0,0,0,0};

    for (int base = start; base < end; base += 64) {
        const int rem = end - base;
        const int n   = rem < 64 ? rem : 64;
        const int nm1 = n - 1;

        int v = 0;
        if (lane < n) v = vals[base + lane];   // one coalesced index load per chunk

        float4 t[16];
        float  w[16];
        #pragma unroll
        for (int k = 0; k < 16; ++k) {
            const int r   = 4 * k + g;
            const int src = r < nm1 ? r : nm1;        // clamp: always a valid lane
            const int idx = __shfl(v, src);           // bpermute broadcast
            t[k] = *(const float4*)(W + (size_t)idx * DIM + s * 4);
            w[k] = (r < n) ? 1.0f : 0.0f;
        }
        #pragma unroll
        for (int k = 0; k < 16; ++k) {
            float4* a = (k & 3) == 0 ? &acc0 : (k & 3) == 1 ? &acc1
                       : (k & 3) == 2 ? &acc2 : &acc3;
            a->x = fmaf(t[k].x, w[k], a->x);
            a->y = fmaf(t[k].y, w[k], a->y);
            a->z = fmaf(t[k].z, w[k], a->z);
            a->w = fmaf(t[k].w, w[k], a->w);
        }
    }

    float4 acc;
    acc.x = (acc0.x + acc1.x) + (acc2.x + acc3.x);
    acc.y = (acc0.y + acc1.y) + (acc2.y + acc3.y);
    acc.z = (acc0.z + acc1.z) + (acc2.z + acc3.z);
    acc.w = (acc0.w + acc1.w) + (acc2.w + acc3.w);

    acc.x += __shfl_xor(acc.x, 16); acc.y += __shfl_xor(acc.y, 16);
    acc.z += __shfl_xor(acc.z, 16); acc.w += __shfl_xor(acc.w, 16);
    acc.x += __shfl_xor(acc.x, 32); acc.y += __shfl_xor(acc.y, 32);
    acc.z += __shfl_xor(acc.z, 32); acc.w += __shfl_xor(acc.w, 32);

    const int cnt = end - start;
    const float inv = cnt > 0 ? 1.0f / (float)cnt : 0.0f;  // empty bag -> zeros

    if (g == 0) {
        float4 r;
        r.x = acc.x * inv; r.y = acc.y * inv; r.z = acc.z * inv; r.w = acc.w * inv;
        *(float4*)(out + (size_t)bag * (4 * DIM) + table * DIM + s * 4) = r;
    }
}

extern "C" void kernel_launch(void* const* d_in, const int* in_sizes, int n_in,
                              void* d_out, int out_size, void* d_ws, size_t ws_size,
                              hipStream_t stream) {
    const float* W0 = (const float*)d_in[0];
    const int*   v0 = (const int*)  d_in[1];
    const int*   o0 = (const int*)  d_in[2];
    const float* W1 = (const float*)d_in[3];
    const int*   v1 = (const int*)  d_in[4];
    const int*   o1 = (const int*)  d_in[5];
    const float* W2 = (const float*)d_in[6];
    const int*   v2 = (const int*)  d_in[7];
    const int*   o2 = (const int*)  d_in[8];
    const float* W3 = (const float*)d_in[9];
    const int*   v3 = (const int*)  d_in[10];
    const int*   o3 = (const int*)  d_in[11];
    float* out = (float*)d_out;

    ebc_kernel<<<NBAGS, 256, 0, stream>>>(W0, v0, o0, W1, v1, o1,
                                          W2, v2, o2, W3, v3, o3, out);
}